// Round 2
// baseline (160.893 us; speedup 1.0000x reference)
//
#include <hip/hip_runtime.h>

#define NN 100
#define CC 32
#define HEE 32
#define FF 64
#define TILE 10

// ---------------- K1: hi = x@ew1[:C]+eb1, hj = x@ew1[C:], d0 ----------------
__global__ __launch_bounds__(64) void k_hidden(
    const float* __restrict__ x, const float* __restrict__ A,
    const float* __restrict__ ew1, const float* __restrict__ eb1,
    float* __restrict__ hi, float* __restrict__ hj, float* __restrict__ d0) {
  int bn = blockIdx.x;
  int t = threadIdx.x;
  __shared__ float xr[CC];
  if (t < CC) xr[t] = x[bn * CC + t];

  const float* arow = A + (size_t)bn * NN;
  float s = 0.f;
  for (int j = t; j < NN; j += 64) s += arow[j];
#pragma unroll
  for (int off = 32; off > 0; off >>= 1) s += __shfl_down(s, off);
  if (t == 0) d0[bn] = 1.0f / sqrtf(s + 1.0f + 1e-5f);

  __syncthreads();
  int k = t & 31;
  const float* w = ew1 + (t < 32 ? 0 : CC * HEE) + k;
  float acc = (t < 32) ? eb1[k] : 0.f;
#pragma unroll
  for (int c = 0; c < CC; ++c) acc += xr[c] * w[c * HEE];
  if (t < 32) hi[bn * HEE + k] = acc;
  else        hj[bn * HEE + k] = acc;
}

// ---------------- K2: Ahat1 = A_pred + I, d1 ----------------
__global__ __launch_bounds__(256) void k_edge(
    const float* __restrict__ hi, const float* __restrict__ hj,
    const float* __restrict__ ew2, const float* __restrict__ eb2,
    const float* __restrict__ mask,
    float* __restrict__ Ahat1, float* __restrict__ d1) {
  __shared__ __align__(16) float shi[NN * HEE];
  __shared__ __align__(16) float shj[NN * HEE];
  __shared__ __align__(16) float sw2[HEE];
  __shared__ float sm[NN];
  __shared__ float sA[TILE][NN];
  int t = threadIdx.x;
  int b = blockIdx.x / 10;
  int i0 = (blockIdx.x % 10) * TILE;

  const float4* hi4 = (const float4*)(hi + (size_t)b * NN * HEE);
  const float4* hj4 = (const float4*)(hj + (size_t)b * NN * HEE);
  float4* shi4 = (float4*)shi;
  float4* shj4 = (float4*)shj;
  for (int v = t; v < NN * 8; v += 256) {
    int j = v >> 3, k4 = v & 7;
    int sw = (j << 3) | (k4 ^ (j & 7));
    shi4[sw] = hi4[v];
    shj4[sw] = hj4[v];
  }
  if (t < HEE) sw2[t] = ew2[t];
  if (t < NN) sm[t] = mask[b * NN + t];
  __syncthreads();

  float e2 = eb2[0];
  float4* sw24 = (float4*)sw2;
  for (int p = t; p < TILE * NN; p += 256) {
    int r = p / NN, j = p % NN, i = i0 + r;
    float val;
    if (j == i) {
      val = 1.0f;
    } else {
      float a1 = 0.f, a2 = 0.f;
#pragma unroll
      for (int k4 = 0; k4 < 8; ++k4) {
        float4 hii = shi4[(i << 3) | (k4 ^ (i & 7))];
        float4 hji = shj4[(i << 3) | (k4 ^ (i & 7))];
        float4 hij = shi4[(j << 3) | (k4 ^ (j & 7))];
        float4 hjj = shj4[(j << 3) | (k4 ^ (j & 7))];
        float4 w4 = sw24[k4];
        a1 += fmaxf(hii.x + hjj.x, 0.f) * w4.x;
        a2 += fmaxf(hij.x + hji.x, 0.f) * w4.x;
        a1 += fmaxf(hii.y + hjj.y, 0.f) * w4.y;
        a2 += fmaxf(hij.y + hji.y, 0.f) * w4.y;
        a1 += fmaxf(hii.z + hjj.z, 0.f) * w4.z;
        a2 += fmaxf(hij.z + hji.z, 0.f) * w4.z;
        a1 += fmaxf(hii.w + hjj.w, 0.f) * w4.w;
        a2 += fmaxf(hij.w + hji.w, 0.f) * w4.w;
      }
      val = expf(0.5f * (a1 + a2) + e2) * sm[i] * sm[j];
    }
    sA[r][j] = val;
    Ahat1[((size_t)b * NN + i) * NN + j] = val;
  }
  __syncthreads();
  if (t < TILE) {
    float s = 0.f;
    for (int j = 0; j < NN; ++j) s += sA[t][j];
    d1[b * NN + i0 + t] = 1.0f / sqrtf(s + 1e-5f);
  }
}

// ---------------- K_pre: P = x @ [gw0_top | gw0_bot]  ([B][2][100][64]) ----------------
__global__ __launch_bounds__(256) void k_pre(
    const float* __restrict__ x, const float* __restrict__ gw0,
    float* __restrict__ P) {
  __shared__ __align__(16) float xT[CC * 64];   // swizzled [k][i]
  __shared__ __align__(16) float sW[CC * 128];  // [k][f']
  int t = threadIdx.x;
  int b = blockIdx.x >> 1;
  int i0 = (blockIdx.x & 1) * 64;

  for (int p = t; p < 64 * CC; p += 256) {
    int i = p >> 5, k = p & 31;
    int row = i0 + i;
    float v = (row < NN) ? x[((size_t)b * NN + row) * CC + k] : 0.f;
    xT[k * 64 + ((((i >> 2) ^ (k & 15)) << 2) | (i & 3))] = v;
  }
  const float4* gw4 = (const float4*)gw0;  // gw0 is [64][64]
  float4* sW4 = (float4*)sW;
  for (int v = t; v < CC * 32; v += 256) {
    int k = v >> 5, f4 = v & 31;
    int rel = f4 >> 4;
    sW4[v] = gw4[(rel * 32 + k) * 16 + (f4 & 15)];
  }
  __syncthreads();

  int igrp = t >> 5, f4g = t & 31;
  int ig = igrp * 8;
  float4 acc[8];
#pragma unroll
  for (int ii = 0; ii < 8; ++ii) acc[ii] = float4{0.f, 0.f, 0.f, 0.f};
  const float4* xT4 = (const float4*)xT;
#pragma unroll 4
  for (int k = 0; k < CC; ++k) {
    int m = k & 15;
    float4 l0 = xT4[k * 16 + ((ig >> 2) ^ m)];
    float4 l1 = xT4[k * 16 + (((ig >> 2) + 1) ^ m)];
    float4 w = sW4[k * 32 + f4g];
    float la[8] = {l0.x, l0.y, l0.z, l0.w, l1.x, l1.y, l1.z, l1.w};
#pragma unroll
    for (int ii = 0; ii < 8; ++ii) {
      acc[ii].x += la[ii] * w.x;
      acc[ii].y += la[ii] * w.y;
      acc[ii].z += la[ii] * w.z;
      acc[ii].w += la[ii] * w.w;
    }
  }
  int rel = f4g >> 4, fl4 = f4g & 15;
  float4* P4 = (float4*)P;
#pragma unroll
  for (int ii = 0; ii < 8; ++ii) {
    int row = i0 + ig + ii;
    if (row < NN) P4[(((size_t)b * 2 + rel) * NN + row) * 16 + fl4] = acc[ii];
  }
}

// ---------------- K_layer: out = relu((L0@P0 + L1@P1 + b)*mask); Pout = out@Wcat_next
// LAST: pooled partial max instead.
template <int LAST>
__global__ __launch_bounds__(256) void k_layer(
    const float* __restrict__ A, const float* __restrict__ Ah1,
    const float* __restrict__ d0, const float* __restrict__ d1,
    const float* __restrict__ mask, const float* __restrict__ Pin,
    const float* __restrict__ bias, const float* __restrict__ Wn,
    float* __restrict__ Pout) {
  // region1: 16384 floats: phase A = sLT[200][64] swz (12800); phase B = red[4][64][64]
  // region2: 12800 floats: phase A = sP[200][64]; phase B/C = outT[64][64] swz (4096) + sW[64][128] (8192)
  __shared__ __align__(16) float r1[16384];
  __shared__ __align__(16) float r2[12800];
  __shared__ float sm[64];
  __shared__ float sbias[64];
  int t = threadIdx.x;
  int b = blockIdx.x >> 1;
  int i0 = (blockIdx.x & 1) * 64;

  const float* d0b = d0 + b * NN;
  const float* d1b = d1 + b * NN;
  for (int p = t; p < 64 * 200; p += 256) {
    int i = p / 200, jp = p % 200;
    int row = i0 + i;
    float L = 0.f;
    if (row < NN) {
      if (jp < NN) {
        float a = A[((size_t)b * NN + row) * NN + jp] + (row == jp ? 1.f : 0.f);
        L = a * d0b[row] * d0b[jp];
      } else {
        int j = jp - NN;
        L = Ah1[((size_t)b * NN + row) * NN + j] * d1b[row] * d1b[j];
      }
    }
    r1[jp * 64 + ((((i >> 2) ^ (jp & 15)) << 2) | (i & 3))] = L;
  }
  float4* r24 = (float4*)r2;
  const float4* Pin4 = (const float4*)(Pin + (size_t)b * 12800);
  for (int v = t; v < 3200; v += 256) r24[v] = Pin4[v];
  if (t < 64) {
    int row = i0 + t;
    sm[t] = (row < NN) ? mask[b * NN + row] : 0.f;
    sbias[t] = bias[t];
  }
  __syncthreads();

  // ---- GEMM2: Lcat[64x200] @ Pcat[200x64], 8i x 8f tiles, k-split 4 ----
  {
    int split = t >> 6;
    int item = t & 63;
    int ig = (item >> 3) << 3;
    int fg = (item & 7) << 3;
    float4 acc[8][2];
#pragma unroll
    for (int ii = 0; ii < 8; ++ii) {
      acc[ii][0] = float4{0.f, 0.f, 0.f, 0.f};
      acc[ii][1] = float4{0.f, 0.f, 0.f, 0.f};
    }
    const float4* lt4 = (const float4*)r1;
    const float4* p4 = (const float4*)r2;
#pragma unroll 2
    for (int jj = 0; jj < 50; ++jj) {
      int j = split * 50 + jj;
      int m = j & 15;
      float4 l0 = lt4[j * 16 + ((ig >> 2) ^ m)];
      float4 l1 = lt4[j * 16 + (((ig >> 2) + 1) ^ m)];
      float4 p0 = p4[j * 16 + (fg >> 2)];
      float4 p1 = p4[j * 16 + ((fg >> 2) + 1)];
      float la[8] = {l0.x, l0.y, l0.z, l0.w, l1.x, l1.y, l1.z, l1.w};
#pragma unroll
      for (int ii = 0; ii < 8; ++ii) {
        acc[ii][0].x += la[ii] * p0.x;
        acc[ii][0].y += la[ii] * p0.y;
        acc[ii][0].z += la[ii] * p0.z;
        acc[ii][0].w += la[ii] * p0.w;
        acc[ii][1].x += la[ii] * p1.x;
        acc[ii][1].y += la[ii] * p1.y;
        acc[ii][1].z += la[ii] * p1.z;
        acc[ii][1].w += la[ii] * p1.w;
      }
    }
    __syncthreads();  // sLT / sP dead
    float4* red4 = (float4*)r1;
#pragma unroll
    for (int ii = 0; ii < 8; ++ii) {
      int base = (split * 4096 + (ig + ii) * 64 + fg) >> 2;
      red4[base] = acc[ii][0];
      red4[base + 1] = acc[ii][1];
    }
  }
  // stage sW (region2 upper; sP is dead) while red lands
  if (!LAST) {
    float4* sW4 = (float4*)(r2 + 4096);
    const float4* Wn4 = (const float4*)Wn;  // Wn is [128][64]
    for (int v = t; v < 2048; v += 256) {
      int k = v >> 5, f4 = v & 31;
      int rel = f4 >> 4;
      sW4[v] = Wn4[(rel * 64 + k) * 16 + (f4 & 15)];
    }
  }
  __syncthreads();  // red complete

  // ---- reduce splits + bias + mask + relu ----
  {
    int f = t & 63;
    int iblk = (t >> 6) * 16;
    float vals[16];
#pragma unroll
    for (int q = 0; q < 16; ++q) {
      int i = iblk + q;
      float v = r1[i * 64 + f] + r1[4096 + i * 64 + f] +
                r1[8192 + i * 64 + f] + r1[12288 + i * 64 + f];
      v = (v + sbias[f]) * sm[i];
      vals[q] = fmaxf(v, 0.f);
    }
    if (LAST) {
      float mx = vals[0];
#pragma unroll
      for (int q = 1; q < 16; ++q) mx = fmaxf(mx, vals[q]);
      r2[(t >> 6) * 64 + f] = mx;
      __syncthreads();
      if (t < 64) {
        float m0 = fmaxf(fmaxf(r2[t], r2[64 + t]), fmaxf(r2[128 + t], r2[192 + t]));
        Pout[((size_t)b * 2 + (i0 >> 6)) * 64 + t] = m0;
      }
      return;
    }
    float4* oT4 = (float4*)r2;
#pragma unroll
    for (int q = 0; q < 4; ++q) {
      float4 v4 = {vals[q * 4], vals[q * 4 + 1], vals[q * 4 + 2], vals[q * 4 + 3]};
      oT4[f * 16 + (((iblk >> 2) + q) ^ (f & 15))] = v4;
    }
  }
  __syncthreads();

  // ---- phase C: Pout_tile = out_tile @ sW  (64x64 @ 64x128) ----
  {
    int igrp = t >> 5, f4g = t & 31;
    int ig = igrp * 8;
    float4 acc[8];
#pragma unroll
    for (int ii = 0; ii < 8; ++ii) acc[ii] = float4{0.f, 0.f, 0.f, 0.f};
    const float4* oT4 = (const float4*)r2;
    const float4* sW4 = (const float4*)(r2 + 4096);
#pragma unroll 4
    for (int k = 0; k < 64; ++k) {
      int m = k & 15;
      float4 l0 = oT4[k * 16 + ((ig >> 2) ^ m)];
      float4 l1 = oT4[k * 16 + (((ig >> 2) + 1) ^ m)];
      float4 w = sW4[k * 32 + f4g];
      float la[8] = {l0.x, l0.y, l0.z, l0.w, l1.x, l1.y, l1.z, l1.w};
#pragma unroll
      for (int ii = 0; ii < 8; ++ii) {
        acc[ii].x += la[ii] * w.x;
        acc[ii].y += la[ii] * w.y;
        acc[ii].z += la[ii] * w.z;
        acc[ii].w += la[ii] * w.w;
      }
    }
    int rel = f4g >> 4, fl4 = f4g & 15;
    float4* Po4 = (float4*)Pout;
#pragma unroll
    for (int ii = 0; ii < 8; ++ii) {
      int row = i0 + ig + ii;
      if (row < NN) Po4[(((size_t)b * 2 + rel) * NN + row) * 16 + fl4] = acc[ii];
    }
  }
}

// ---------------- K_final: combine 2 pooled partials + classifier ----------------
__global__ __launch_bounds__(64) void k_final(
    const float* __restrict__ pooled, const float* __restrict__ fw,
    const float* __restrict__ fb, float* __restrict__ out) {
  int b = blockIdx.x;
  int t = threadIdx.x;
  __shared__ float sp[FF];
  float m = fmaxf(pooled[(size_t)b * 128 + t], pooled[(size_t)b * 128 + 64 + t]);
  sp[t] = m;
  __syncthreads();
  if (t < 16) {
    float acc = fb[t];
#pragma unroll
    for (int f = 0; f < FF; ++f) acc += sp[f] * fw[f * 16 + t];
    out[b * 16 + t] = acc;
  }
}

extern "C" void kernel_launch(void* const* d_in, const int* in_sizes, int n_in,
                              void* d_out, int out_size, void* d_ws, size_t ws_size,
                              hipStream_t stream) {
  const float* x    = (const float*)d_in[0];
  const float* A    = (const float*)d_in[1];
  const float* mask = (const float*)d_in[2];
  const float* ew1  = (const float*)d_in[3];
  const float* eb1  = (const float*)d_in[4];
  const float* ew2  = (const float*)d_in[5];
  const float* eb2  = (const float*)d_in[6];
  const float* gw0  = (const float*)d_in[7];
  const float* gb0  = (const float*)d_in[8];
  const float* gw1  = (const float*)d_in[9];
  const float* gb1  = (const float*)d_in[10];
  const float* gw2  = (const float*)d_in[11];
  const float* gb2  = (const float*)d_in[12];
  const float* fw   = (const float*)d_in[13];
  const float* fb   = (const float*)d_in[14];
  float* out = (float*)d_out;
  float* ws = (float*)d_ws;

  const int B = 128;
  float* hi  = ws;                   // 409600
  float* hj  = hi + 409600;          // 409600
  float* Ah1 = hj + 409600;          // 1280000
  float* d0  = Ah1 + 1280000;        // 12800
  float* d1  = d0 + 12800;           // 12800
  float* Pa  = d1 + 12800;           // 1638400  [B][2][100][64]
  float* Pb  = Pa + 1638400;         // 1638400
  float* pooled = Pb + 1638400;      // 128*2*64 = 16384

  k_hidden<<<B * NN, 64, 0, stream>>>(x, A, ew1, eb1, hi, hj, d0);
  k_edge<<<B * 10, 256, 0, stream>>>(hi, hj, ew2, eb2, mask, Ah1, d1);
  k_pre<<<B * 2, 256, 0, stream>>>(x, gw0, Pa);
  k_layer<0><<<B * 2, 256, 0, stream>>>(A, Ah1, d0, d1, mask, Pa, gb0, gw1, Pb);
  k_layer<0><<<B * 2, 256, 0, stream>>>(A, Ah1, d0, d1, mask, Pb, gb1, gw2, Pa);
  k_layer<1><<<B * 2, 256, 0, stream>>>(A, Ah1, d0, d1, mask, Pa, gb2, gw2, pooled);
  k_final<<<B, 64, 0, stream>>>(pooled, fw, fb, out);
}